// Round 2
// baseline (135.202 us; speedup 1.0000x reference)
//
#include <hip/hip_runtime.h>
#include <math.h>

// One thread per edge. Packed-fp32 (v_pk_fma_f32) version: accumulators for
// the two big einsums are float2 ext-vectors packed along output dims whose
// weights are memory-consecutive (k for W1_sso/W1_vvo/W1_svv/W1_vsv/W2_svv,
// o for W2_sso/W2_vvo). Weight pairs load as uniform s_loads into SGPR pairs;
// per-edge scalars enter as splats (op_sel-folded). Layer-1 os production is
// fused into layer-2 consumption per k2-pair to cut register liveness.

typedef float f2 __attribute__((ext_vector_type(2)));

static __device__ __forceinline__ f2 sp(float x) { return (f2){x, x}; }
static __device__ __forceinline__ f2 pfma(f2 a, f2 b, f2 c) {
    return __builtin_elementwise_fma(a, b, c);
}
static __device__ __forceinline__ f2 wp(const float* __restrict__ p) {
    return (f2){p[0], p[1]};
}

__global__ __launch_bounds__(256, 4) void fds_kernel(
    const float* __restrict__ lig, const float* __restrict__ rec,
    const float* __restrict__ W1_sso, const float* __restrict__ W1_svv,
    const float* __restrict__ W1_vsv, const float* __restrict__ W1_vvo,
    const float* __restrict__ W1_vvv, const float* __restrict__ W2_sso,
    const float* __restrict__ W2_svv, const float* __restrict__ W2_vsv,
    const float* __restrict__ W2_vvo, const float* __restrict__ W2_vvv,
    float* __restrict__ out, int E)
{
    const float INV_SQRT2   = 0.70710678118654752f;
    const float INV_SQRT3   = 0.57735026918962576f;
    const float INV_SQRT21  = 0.21821789023599239f;
    const float INV_SQRT10  = 0.31622776601683794f;
    const float INV_SQRT105 = 0.09759000729485332f;
    const float INV_SQRT50  = 0.14142135623730950f;
    const float C5 = -0.32f;                 // -0.5 / 1.25^2
    const float OFF4 = 5.0f / 3.0f;
    const float C4 = -0.5f / (OFF4 * OFF4);

    int e = blockIdx.x * blockDim.x + threadIdx.x;
    if (e >= E) return;

    const float4* lp = (const float4*)lig + 3 * (size_t)e;
    const float4* rp = (const float4*)rec + 3 * (size_t)e;
    float4 l0 = lp[0], l1 = lp[1], l2 = lp[2];
    float4 r0 = rp[0], r1 = rp[1], r2 = rp[2];

    // row 4e+1 = floats 3..5, row 4e+2 = floats 6..8, row 4e+3 = floats 9..11
    float e1x = l0.w - r0.w, e1y = l1.x - r1.x, e1z = l1.y - r1.y;
    float e2x = l1.z - r1.z, e2y = l1.w - r1.w, e2z = l2.x - r2.x;
    float e3x = l2.y - r2.y, e3y = l2.z - r2.z, e3z = l2.w - r2.w;

    float q1 = fmaf(e1x, e1x, fmaf(e1y, e1y, e1z * e1z)) + 1e-12f;
    float q2 = fmaf(e2x, e2x, fmaf(e2y, e2y, e2z * e2z)) + 1e-12f;
    float q3 = fmaf(e3x, e3x, fmaf(e3y, e3y, e3z * e3z)) + 1e-12f;
    float ri1 = rsqrtf(q1), ri2 = rsqrtf(q2), ri3 = rsqrtf(q3);
    float d1 = q1 * ri1, d2 = q2 * ri2, d3 = q3 * ri3;
    float v1x = e1x * ri1, v1y = e1y * ri1, v1z = e1z * ri1;
    float v2x = e2x * ri2, v2y = e2y * ri2, v2z = e2z * ri2;
    float v3x = e3x * ri3, v3y = e3y * ri3, v3z = e3z * ri3;

    float s1[5], s3[5], s2[4];
#pragma unroll
    for (int i = 0; i < 5; i++) { float t = d1 - 1.25f * i; s1[i] = __expf(C5 * t * t); }
#pragma unroll
    for (int i = 0; i < 5; i++) { float t = d3 - 1.25f * i; s3[i] = __expf(C5 * t * t); }
#pragma unroll
    for (int j = 0; j < 4; j++) { float t = d2 - OFF4 * j; s2[j] = __expf(C4 * t * t); }

    float dot12 = fmaf(v1x, v2x, fmaf(v1y, v2y, v1z * v2z)) * INV_SQRT3;
    float cr12x = (v1y * v2z - v1z * v2y) * INV_SQRT2;
    float cr12y = (v1z * v2x - v1x * v2z) * INV_SQRT2;
    float cr12z = (v1x * v2y - v1y * v2x) * INV_SQRT2;

    // ---- layer 1 vector path: A = s1·W1_svv, B = s2·W1_vsv (packed over k)
    f2 A01 = {0.f, 0.f}, A23 = {0.f, 0.f};
    float A4 = 0.f;
#pragma unroll
    for (int i = 0; i < 5; i++) {
        f2 si = sp(s1[i]);
        A01 = pfma(si, wp(W1_svv + i * 5 + 0), A01);
        A23 = pfma(si, wp(W1_svv + i * 5 + 2), A23);
        A4  = fmaf(s1[i], W1_svv[i * 5 + 4], A4);
    }
    f2 B01 = {0.f, 0.f}, B23 = {0.f, 0.f};
    float B4 = 0.f;
#pragma unroll
    for (int j = 0; j < 4; j++) {
        f2 sj = sp(s2[j]);
        B01 = pfma(sj, wp(W1_vsv + j * 5 + 0), B01);
        B23 = pfma(sj, wp(W1_vsv + j * 5 + 2), B23);
        B4  = fmaf(s2[j], W1_vsv[j * 5 + 4], B4);
    }
    float A[5] = {A01.x, A01.y, A23.x, A23.y, A4};
    float B[5] = {B01.x, B01.y, B23.x, B23.y, B4};

    float ov[5][3];
#pragma unroll
    for (int k = 0; k < 5; k++) {
        float w = W1_vvv[k];
        ov[k][0] = fmaf(A[k], v2x, fmaf(B[k], v1x, cr12x * w)) * INV_SQRT10;
        ov[k][1] = fmaf(A[k], v2y, fmaf(B[k], v1y, cr12y * w)) * INV_SQRT10;
        ov[k][2] = fmaf(A[k], v2z, fmaf(B[k], v1z, cr12z * w)) * INV_SQRT10;
    }

    // ---- layer 2 vector-derived pieces
    float dot2[5];
#pragma unroll
    for (int k = 0; k < 5; k++)
        dot2[k] = fmaf(ov[k][0], v3x, fmaf(ov[k][1], v3y, ov[k][2] * v3z)) * INV_SQRT3;

    // accs init from dot2 · W2_vvo (packed over o)
    f2 acc01 = {0.f, 0.f}, acc23 = {0.f, 0.f}, acc45 = {0.f, 0.f}, acc67 = {0.f, 0.f};
    float acc8 = 0.f;
#pragma unroll
    for (int k = 0; k < 5; k++) {
        f2 dk = sp(dot2[k]);
        const float* w = W2_vvo + k * 9;
        acc01 = pfma(dk, wp(w + 0), acc01);
        acc23 = pfma(dk, wp(w + 2), acc23);
        acc45 = pfma(dk, wp(w + 4), acc45);
        acc67 = pfma(dk, wp(w + 6), acc67);
        acc8  = fmaf(dot2[k], w[8], acc8);
    }

    // av partial: ov·Ck + cross2·W2_vvv (S·v3 added at the end)
    float av0 = 0.f, av1 = 0.f, av2 = 0.f;
#pragma unroll
    for (int k = 0; k < 5; k++) {
        float c = 0.f;
#pragma unroll
        for (int j = 0; j < 5; j++) c = fmaf(s3[j], W2_vsv[k * 5 + j], c);
        float w = W2_vvv[k];
        float cx = (ov[k][1] * v3z - ov[k][2] * v3y) * INV_SQRT2;
        float cy = (ov[k][2] * v3x - ov[k][0] * v3z) * INV_SQRT2;
        float cz = (ov[k][0] * v3y - ov[k][1] * v3x) * INV_SQRT2;
        av0 = fmaf(ov[k][0], c, fmaf(cx, w, av0));
        av1 = fmaf(ov[k][1], c, fmaf(cy, w, av1));
        av2 = fmaf(ov[k][2], c, fmaf(cz, w, av2));
    }

    // ---- scalar pathway: p12, then fused per-k2-pair produce/consume of os
    float p12[20];
#pragma unroll
    for (int i = 0; i < 5; i++)
#pragma unroll
        for (int j = 0; j < 4; j++) p12[i * 4 + j] = s1[i] * s2[j];

    f2 Sp = {0.f, 0.f};
    f2 c21 = sp(INV_SQRT21);
#pragma unroll
    for (int k2p = 0; k2p < 10; k2p++) {
        const int k2 = 2 * k2p;
        // os pair = (dot12*W1_vvo + p12·W1_sso[:,k2:k2+2]) * inv_sqrt21
        f2 os = sp(dot12) * wp(W1_vvo + k2);
#pragma unroll
        for (int ij = 0; ij < 20; ij++)
            os = pfma(sp(p12[ij]), wp(W1_sso + ij * 20 + k2), os);
        os = os * c21;
        // S accumulation (packed)
        Sp = pfma(os, wp(W2_svv + k2), Sp);
        // layer-2 scalar einsum consumption (packed over o)
#pragma unroll
        for (int j = 0; j < 5; j++) {
            f2 fj = os * sp(s3[j]);
            const float* wa = W2_sso + ((size_t)k2 * 5 + j) * 9;
            const float* wb = wa + 45;
            f2 fx = sp(fj.x), fy = sp(fj.y);
            acc01 = pfma(fx, wp(wa + 0), acc01);
            acc23 = pfma(fx, wp(wa + 2), acc23);
            acc45 = pfma(fx, wp(wa + 4), acc45);
            acc67 = pfma(fx, wp(wa + 6), acc67);
            acc8  = fmaf(fj.x, wa[8], acc8);
            acc01 = pfma(fy, wp(wb + 0), acc01);
            acc23 = pfma(fy, wp(wb + 2), acc23);
            acc45 = pfma(fy, wp(wb + 4), acc45);
            acc67 = pfma(fy, wp(wb + 6), acc67);
            acc8  = fmaf(fj.y, wb[8], acc8);
        }
    }
    float S = Sp.x + Sp.y;
    av0 = fmaf(S, v3x, av0);
    av1 = fmaf(S, v3y, av1);
    av2 = fmaf(S, v3z, av2);

    size_t E3 = (size_t)E * 3;
    size_t b = (size_t)e * 3;
    out[b + 0]          = acc01.x * INV_SQRT105;   // s_rot
    out[b + 1]          = acc01.y * INV_SQRT105;
    out[b + 2]          = acc23.x * INV_SQRT105;
    out[E3 + b + 0]     = acc23.y * INV_SQRT105;   // s_tr
    out[E3 + b + 1]     = acc45.x * INV_SQRT105;
    out[E3 + b + 2]     = acc45.y * INV_SQRT105;
    out[2 * E3 + b + 0] = acc67.x * INV_SQRT105;   // t_rot
    out[2 * E3 + b + 1] = acc67.y * INV_SQRT105;
    out[2 * E3 + b + 2] = acc8   * INV_SQRT105;
    out[3 * E3 + b + 0] = av0 * INV_SQRT50;        // t_tr
    out[3 * E3 + b + 1] = av1 * INV_SQRT50;
    out[3 * E3 + b + 2] = av2 * INV_SQRT50;
}

extern "C" void kernel_launch(void* const* d_in, const int* in_sizes, int n_in,
                              void* d_out, int out_size, void* d_ws, size_t ws_size,
                              hipStream_t stream) {
    const float* lig    = (const float*)d_in[0];
    const float* rec    = (const float*)d_in[1];
    const float* W1_sso = (const float*)d_in[2];
    const float* W1_svv = (const float*)d_in[3];
    const float* W1_vsv = (const float*)d_in[4];
    const float* W1_vvo = (const float*)d_in[5];
    const float* W1_vvv = (const float*)d_in[6];
    const float* W2_sso = (const float*)d_in[7];
    const float* W2_svv = (const float*)d_in[8];
    const float* W2_vsv = (const float*)d_in[9];
    const float* W2_vvo = (const float*)d_in[10];
    const float* W2_vvv = (const float*)d_in[11];

    int E = in_sizes[0] / 12;  // N*3 / 12 = N/4
    int blocks = (E + 255) / 256;
    fds_kernel<<<blocks, 256, 0, stream>>>(lig, rec, W1_sso, W1_svv, W1_vsv,
                                           W1_vvo, W1_vvv, W2_sso, W2_svv,
                                           W2_vsv, W2_vvo, W2_vvv,
                                           (float*)d_out, E);
}

// Round 3
// 119.250 us; speedup vs baseline: 1.1338x; 1.1338x over previous
//
#include <hip/hip_runtime.h>
#include <math.h>

// One thread per PAIR of edges (2t, 2t+1). All ALU is plain scalar fmaf
// (gfx950 fast path). The two big contractions (W1_sso: 400 MAC/edge,
// W2_sso: 900 MAC/edge) interleave both edges inside each weight-load loop,
// so each uniform weight load feeds 2 FMAs -> per-edge load count halves vs
// one-edge-per-thread. Liveness ordered so ov[] dies before p12[] is built.

__global__ __launch_bounds__(256, 4) void fds_kernel(
    const float* __restrict__ lig, const float* __restrict__ rec,
    const float* __restrict__ W1_sso, const float* __restrict__ W1_svv,
    const float* __restrict__ W1_vsv, const float* __restrict__ W1_vvo,
    const float* __restrict__ W1_vvv, const float* __restrict__ W2_sso,
    const float* __restrict__ W2_svv, const float* __restrict__ W2_vsv,
    const float* __restrict__ W2_vvo, const float* __restrict__ W2_vvv,
    float* __restrict__ out, int E)
{
    const float INV_SQRT2   = 0.70710678118654752f;
    const float INV_SQRT3   = 0.57735026918962576f;
    const float INV_SQRT21  = 0.21821789023599239f;
    const float INV_SQRT10  = 0.31622776601683794f;
    const float INV_SQRT105 = 0.09759000729485332f;
    const float INV_SQRT50  = 0.14142135623730950f;
    const float C5 = -0.32f;                 // -0.5 / 1.25^2
    const float OFF4 = 5.0f / 3.0f;
    const float C4 = -0.5f / (OFF4 * OFF4);

    int t = blockIdx.x * blockDim.x + threadIdx.x;
    int P = E >> 1;
    if (t >= P) return;

    // ---- load 2 edges' worth of positions: rows 8t..8t+7 = 24 floats each
    const float4* lp = (const float4*)lig + 6 * (size_t)t;
    const float4* rp = (const float4*)rec + 6 * (size_t)t;
    float f[24], g[24];
#pragma unroll
    for (int q = 0; q < 6; q++) {
        float4 a = lp[q], b = rp[q];
        f[4 * q + 0] = a.x; f[4 * q + 1] = a.y; f[4 * q + 2] = a.z; f[4 * q + 3] = a.w;
        g[4 * q + 0] = b.x; g[4 * q + 1] = b.y; g[4 * q + 2] = b.z; g[4 * q + 3] = b.w;
    }

    // ---- per-edge geometry
    float s1[2][5], s2[2][4], s3[2][5];
    float v1[2][3], v2[2][3], v3[2][3];
    float dot12[2], cr12[2][3];
#pragma unroll
    for (int u = 0; u < 2; u++) {
        const int b = 12 * u;
        float e1x = f[b+3] - g[b+3], e1y = f[b+4]  - g[b+4],  e1z = f[b+5]  - g[b+5];
        float e2x = f[b+6] - g[b+6], e2y = f[b+7]  - g[b+7],  e2z = f[b+8]  - g[b+8];
        float e3x = f[b+9] - g[b+9], e3y = f[b+10] - g[b+10], e3z = f[b+11] - g[b+11];
        float q1 = fmaf(e1x, e1x, fmaf(e1y, e1y, e1z * e1z)) + 1e-12f;
        float q2 = fmaf(e2x, e2x, fmaf(e2y, e2y, e2z * e2z)) + 1e-12f;
        float q3 = fmaf(e3x, e3x, fmaf(e3y, e3y, e3z * e3z)) + 1e-12f;
        float ri1 = rsqrtf(q1), ri2 = rsqrtf(q2), ri3 = rsqrtf(q3);
        float d1 = q1 * ri1, d2 = q2 * ri2, d3 = q3 * ri3;
        v1[u][0] = e1x * ri1; v1[u][1] = e1y * ri1; v1[u][2] = e1z * ri1;
        v2[u][0] = e2x * ri2; v2[u][1] = e2y * ri2; v2[u][2] = e2z * ri2;
        v3[u][0] = e3x * ri3; v3[u][1] = e3y * ri3; v3[u][2] = e3z * ri3;
#pragma unroll
        for (int i = 0; i < 5; i++) { float x = d1 - 1.25f * i; s1[u][i] = __expf(C5 * x * x); }
#pragma unroll
        for (int i = 0; i < 5; i++) { float x = d3 - 1.25f * i; s3[u][i] = __expf(C5 * x * x); }
#pragma unroll
        for (int j = 0; j < 4; j++) { float x = d2 - OFF4 * j; s2[u][j] = __expf(C4 * x * x); }
        dot12[u] = fmaf(v1[u][0], v2[u][0], fmaf(v1[u][1], v2[u][1], v1[u][2] * v2[u][2])) * INV_SQRT3;
        cr12[u][0] = (v1[u][1] * v2[u][2] - v1[u][2] * v2[u][1]) * INV_SQRT2;
        cr12[u][1] = (v1[u][2] * v2[u][0] - v1[u][0] * v2[u][2]) * INV_SQRT2;
        cr12[u][2] = (v1[u][0] * v2[u][1] - v1[u][1] * v2[u][0]) * INV_SQRT2;
    }

    // ---- layer 1 vector path: A = s1·W1_svv, B = s2·W1_vsv (loads shared)
    float A[2][5], B[2][5];
#pragma unroll
    for (int k = 0; k < 5; k++) { A[0][k] = 0.f; A[1][k] = 0.f; B[0][k] = 0.f; B[1][k] = 0.f; }
#pragma unroll
    for (int i = 0; i < 5; i++)
#pragma unroll
        for (int k = 0; k < 5; k++) {
            float w = W1_svv[i * 5 + k];
            A[0][k] = fmaf(s1[0][i], w, A[0][k]);
            A[1][k] = fmaf(s1[1][i], w, A[1][k]);
        }
#pragma unroll
    for (int j = 0; j < 4; j++)
#pragma unroll
        for (int k = 0; k < 5; k++) {
            float w = W1_vsv[j * 5 + k];
            B[0][k] = fmaf(s2[0][j], w, B[0][k]);
            B[1][k] = fmaf(s2[1][j], w, B[1][k]);
        }

    float ov[2][5][3];
#pragma unroll
    for (int k = 0; k < 5; k++) {
        float w = W1_vvv[k];
#pragma unroll
        for (int u = 0; u < 2; u++) {
#pragma unroll
            for (int c = 0; c < 3; c++)
                ov[u][k][c] = fmaf(A[u][k], v2[u][c], fmaf(B[u][k], v1[u][c], cr12[u][c] * w)) * INV_SQRT10;
        }
    }

    // ---- dot2, accs init (dot2·W2_vvo), av partial (ov·Ck + cross2·W2_vvv)
    float dot2[2][5];
#pragma unroll
    for (int u = 0; u < 2; u++)
#pragma unroll
        for (int k = 0; k < 5; k++)
            dot2[u][k] = fmaf(ov[u][k][0], v3[u][0],
                         fmaf(ov[u][k][1], v3[u][1], ov[u][k][2] * v3[u][2])) * INV_SQRT3;

    float accs[2][9];
#pragma unroll
    for (int o = 0; o < 9; o++) { accs[0][o] = 0.f; accs[1][o] = 0.f; }
#pragma unroll
    for (int k = 0; k < 5; k++)
#pragma unroll
        for (int o = 0; o < 9; o++) {
            float w = W2_vvo[k * 9 + o];
            accs[0][o] = fmaf(dot2[0][k], w, accs[0][o]);
            accs[1][o] = fmaf(dot2[1][k], w, accs[1][o]);
        }

    float av[2][3];
#pragma unroll
    for (int u = 0; u < 2; u++) { av[u][0] = 0.f; av[u][1] = 0.f; av[u][2] = 0.f; }
#pragma unroll
    for (int k = 0; k < 5; k++) {
        float c0 = 0.f, c1 = 0.f;
#pragma unroll
        for (int j = 0; j < 5; j++) {
            float w = W2_vsv[k * 5 + j];
            c0 = fmaf(s3[0][j], w, c0);
            c1 = fmaf(s3[1][j], w, c1);
        }
        float wv = W2_vvv[k];
#pragma unroll
        for (int u = 0; u < 2; u++) {
            float c = u ? c1 : c0;
            float cx = (ov[u][k][1] * v3[u][2] - ov[u][k][2] * v3[u][1]) * INV_SQRT2;
            float cy = (ov[u][k][2] * v3[u][0] - ov[u][k][0] * v3[u][2]) * INV_SQRT2;
            float cz = (ov[u][k][0] * v3[u][1] - ov[u][k][1] * v3[u][0]) * INV_SQRT2;
            av[u][0] = fmaf(ov[u][k][0], c, fmaf(cx, wv, av[u][0]));
            av[u][1] = fmaf(ov[u][k][1], c, fmaf(cy, wv, av[u][1]));
            av[u][2] = fmaf(ov[u][k][2], c, fmaf(cz, wv, av[u][2]));
        }
    }
    // ov dead from here

    // ---- p12 (built late to keep liveness down)
    float p12[2][20];
#pragma unroll
    for (int u = 0; u < 2; u++)
#pragma unroll
        for (int i = 0; i < 5; i++)
#pragma unroll
            for (int j = 0; j < 4; j++) p12[u][i * 4 + j] = s1[u][i] * s2[u][j];

    // ---- fused: per k2 produce os (W1_sso col) and consume (S, W2_sso)
    float S[2] = {0.f, 0.f};
#pragma unroll
    for (int k2 = 0; k2 < 20; k2++) {
        float os0 = dot12[0] * W1_vvo[k2];
        float os1 = dot12[1] * W1_vvo[k2];
#pragma unroll
        for (int ij = 0; ij < 20; ij++) {
            float w = W1_sso[ij * 20 + k2];
            os0 = fmaf(p12[0][ij], w, os0);
            os1 = fmaf(p12[1][ij], w, os1);
        }
        os0 *= INV_SQRT21; os1 *= INV_SQRT21;
        {
            float w = W2_svv[k2];
            S[0] = fmaf(os0, w, S[0]);
            S[1] = fmaf(os1, w, S[1]);
        }
#pragma unroll
        for (int j = 0; j < 5; j++) {
            float f0 = os0 * s3[0][j];
            float f1 = os1 * s3[1][j];
            const float* wb = W2_sso + (k2 * 5 + j) * 9;
#pragma unroll
            for (int o = 0; o < 9; o++) {
                float w = wb[o];
                accs[0][o] = fmaf(f0, w, accs[0][o]);
                accs[1][o] = fmaf(f1, w, accs[1][o]);
            }
        }
    }
#pragma unroll
    for (int u = 0; u < 2; u++) {
        av[u][0] = fmaf(S[u], v3[u][0], av[u][0]);
        av[u][1] = fmaf(S[u], v3[u][1], av[u][1]);
        av[u][2] = fmaf(S[u], v3[u][2], av[u][2]);
    }

    // ---- results: res[u][0..8] = accs*c105 (s_rot,s_tr,t_rot), [9..11] = av*c50
    float res[2][12];
#pragma unroll
    for (int u = 0; u < 2; u++) {
#pragma unroll
        for (int o = 0; o < 9; o++) res[u][o] = accs[u][o] * INV_SQRT105;
#pragma unroll
        for (int c = 0; c < 3; c++) res[u][9 + c] = av[u][c] * INV_SQRT50;
    }

    size_t E3 = (size_t)E * 3;
#pragma unroll
    for (int s = 0; s < 4; s++) {
        float2* dst = (float2*)(out + (size_t)s * E3 + 6 * (size_t)t);
        dst[0] = make_float2(res[0][3 * s + 0], res[0][3 * s + 1]);
        dst[1] = make_float2(res[0][3 * s + 2], res[1][3 * s + 0]);
        dst[2] = make_float2(res[1][3 * s + 1], res[1][3 * s + 2]);
    }
}

extern "C" void kernel_launch(void* const* d_in, const int* in_sizes, int n_in,
                              void* d_out, int out_size, void* d_ws, size_t ws_size,
                              hipStream_t stream) {
    const float* lig    = (const float*)d_in[0];
    const float* rec    = (const float*)d_in[1];
    const float* W1_sso = (const float*)d_in[2];
    const float* W1_svv = (const float*)d_in[3];
    const float* W1_vsv = (const float*)d_in[4];
    const float* W1_vvo = (const float*)d_in[5];
    const float* W1_vvv = (const float*)d_in[6];
    const float* W2_sso = (const float*)d_in[7];
    const float* W2_svv = (const float*)d_in[8];
    const float* W2_vsv = (const float*)d_in[9];
    const float* W2_vvo = (const float*)d_in[10];
    const float* W2_vvv = (const float*)d_in[11];

    int E = in_sizes[0] / 12;  // N*3 / 12 = N/4
    int P = E >> 1;            // E is even (N = 4M)
    int blocks = (P + 255) / 256;
    fds_kernel<<<blocks, 256, 0, stream>>>(lig, rec, W1_sso, W1_svv, W1_vsv,
                                           W1_vvo, W1_vvv, W2_sso, W2_svv,
                                           W2_vsv, W2_vvo, W2_vvv,
                                           (float*)d_out, E);
}

// Round 4
// 56.502 us; speedup vs baseline: 2.3929x; 2.1106x over previous
//
#include <hip/hip_runtime.h>
#include <math.h>

// R1 structure (1 edge/thread, scalar fmaf, 48 VGPR, no spills) + offline
// weight composition: layer-1 scalar output os feeds layer 2 only linearly,
// so W12 = W1_sso @ W2_sso (20x5x9), WV = W1_vvo @ W2_sso (5x9),
// WS = W1_sso @ W2_svv (20), cS = W1_vvo . W2_svv are precomposed (x 1/sqrt21)
// by a tiny prologue kernel into d_ws. Removes the 400-FMA os loop entirely.

#define WS_W12 0      // [20][5][9] = 900
#define WS_WV  900    // [5][9]     = 45
#define WS_WS  945    // [20]       = 20
#define WS_CS  965    // scalar
#define WS_TOT 966

__global__ __launch_bounds__(256) void fds_precompose(
    const float* __restrict__ W1_sso, const float* __restrict__ W1_vvo,
    const float* __restrict__ W2_sso, const float* __restrict__ W2_svv,
    float* __restrict__ ws)
{
    const float INV_SQRT21 = 0.21821789023599239f;
    int tid = threadIdx.x;
    for (int idx = tid; idx < 900; idx += 256) {
        int o = idx % 9, j3 = (idx / 9) % 5, ij = idx / 45;
        float acc = 0.f;
        for (int k2 = 0; k2 < 20; k2++)
            acc = fmaf(W1_sso[ij * 20 + k2], W2_sso[(k2 * 5 + j3) * 9 + o], acc);
        ws[WS_W12 + idx] = acc * INV_SQRT21;
    }
    for (int idx = tid; idx < 45; idx += 256) {
        int o = idx % 9, j3 = idx / 9;
        float acc = 0.f;
        for (int k2 = 0; k2 < 20; k2++)
            acc = fmaf(W1_vvo[k2], W2_sso[(k2 * 5 + j3) * 9 + o], acc);
        ws[WS_WV + idx] = acc * INV_SQRT21;
    }
    for (int idx = tid; idx < 20; idx += 256) {
        float acc = 0.f;
        for (int k2 = 0; k2 < 20; k2++)
            acc = fmaf(W1_sso[idx * 20 + k2], W2_svv[k2], acc);
        ws[WS_WS + idx] = acc * INV_SQRT21;
    }
    if (tid == 0) {
        float acc = 0.f;
        for (int k2 = 0; k2 < 20; k2++) acc = fmaf(W1_vvo[k2], W2_svv[k2], acc);
        ws[WS_CS] = acc * INV_SQRT21;
    }
}

__global__ __launch_bounds__(256) void fds_kernel(
    const float* __restrict__ lig, const float* __restrict__ rec,
    const float* __restrict__ W1_svv, const float* __restrict__ W1_vsv,
    const float* __restrict__ W1_vvv, const float* __restrict__ W2_vsv,
    const float* __restrict__ W2_vvo, const float* __restrict__ W2_vvv,
    const float* __restrict__ ws,
    float* __restrict__ out, int E)
{
    const float INV_SQRT2   = 0.70710678118654752f;
    const float INV_SQRT3   = 0.57735026918962576f;
    const float INV_SQRT10  = 0.31622776601683794f;
    const float INV_SQRT105 = 0.09759000729485332f;
    const float INV_SQRT50  = 0.14142135623730950f;
    const float C5 = -0.32f;                 // -0.5 / 1.25^2
    const float OFF4 = 5.0f / 3.0f;
    const float C4 = -0.5f / (OFF4 * OFF4);

    const float* __restrict__ W12 = ws + WS_W12;
    const float* __restrict__ WV  = ws + WS_WV;
    const float* __restrict__ WSp = ws + WS_WS;

    int e = blockIdx.x * blockDim.x + threadIdx.x;
    if (e >= E) return;

    const float4* lp = (const float4*)lig + 3 * (size_t)e;
    const float4* rp = (const float4*)rec + 3 * (size_t)e;
    float4 l0 = lp[0], l1 = lp[1], l2 = lp[2];
    float4 r0 = rp[0], r1 = rp[1], r2 = rp[2];

    // row 4e+1 = floats 3..5, row 4e+2 = floats 6..8, row 4e+3 = floats 9..11
    float e1x = l0.w - r0.w, e1y = l1.x - r1.x, e1z = l1.y - r1.y;
    float e2x = l1.z - r1.z, e2y = l1.w - r1.w, e2z = l2.x - r2.x;
    float e3x = l2.y - r2.y, e3y = l2.z - r2.z, e3z = l2.w - r2.w;

    float q1 = fmaf(e1x, e1x, fmaf(e1y, e1y, e1z * e1z)) + 1e-12f;
    float q2 = fmaf(e2x, e2x, fmaf(e2y, e2y, e2z * e2z)) + 1e-12f;
    float q3 = fmaf(e3x, e3x, fmaf(e3y, e3y, e3z * e3z)) + 1e-12f;
    float ri1 = rsqrtf(q1), ri2 = rsqrtf(q2), ri3 = rsqrtf(q3);
    float d1 = q1 * ri1, d2 = q2 * ri2, d3 = q3 * ri3;
    float v1x = e1x * ri1, v1y = e1y * ri1, v1z = e1z * ri1;
    float v2x = e2x * ri2, v2y = e2y * ri2, v2z = e2z * ri2;
    float v3x = e3x * ri3, v3y = e3y * ri3, v3z = e3z * ri3;

    float s1[5], s3[5], s2[4];
#pragma unroll
    for (int i = 0; i < 5; i++) { float t = d1 - 1.25f * i; s1[i] = __expf(C5 * t * t); }
#pragma unroll
    for (int i = 0; i < 5; i++) { float t = d3 - 1.25f * i; s3[i] = __expf(C5 * t * t); }
#pragma unroll
    for (int j = 0; j < 4; j++) { float t = d2 - OFF4 * j; s2[j] = __expf(C4 * t * t); }

    float dot12 = fmaf(v1x, v2x, fmaf(v1y, v2y, v1z * v2z)) * INV_SQRT3;
    float cr12x = (v1y * v2z - v1z * v2y) * INV_SQRT2;
    float cr12y = (v1z * v2x - v1x * v2z) * INV_SQRT2;
    float cr12z = (v1x * v2y - v1y * v2x) * INV_SQRT2;

    // layer 1 vector path
    float A[5], B[5];
#pragma unroll
    for (int k = 0; k < 5; k++) {
        float a = 0.f, b = 0.f;
#pragma unroll
        for (int i = 0; i < 5; i++) a = fmaf(s1[i], W1_svv[i * 5 + k], a);
#pragma unroll
        for (int j = 0; j < 4; j++) b = fmaf(s2[j], W1_vsv[j * 5 + k], b);
        A[k] = a; B[k] = b;
    }
    float ov[5][3];
#pragma unroll
    for (int k = 0; k < 5; k++) {
        float w = W1_vvv[k];
        ov[k][0] = fmaf(A[k], v2x, fmaf(B[k], v1x, cr12x * w)) * INV_SQRT10;
        ov[k][1] = fmaf(A[k], v2y, fmaf(B[k], v1y, cr12y * w)) * INV_SQRT10;
        ov[k][2] = fmaf(A[k], v2z, fmaf(B[k], v1z, cr12z * w)) * INV_SQRT10;
    }

    // layer 2 vector-derived pieces
    float dot2[5];
#pragma unroll
    for (int k = 0; k < 5; k++)
        dot2[k] = fmaf(ov[k][0], v3x, fmaf(ov[k][1], v3y, ov[k][2] * v3z)) * INV_SQRT3;

    float accs[9];
#pragma unroll
    for (int o = 0; o < 9; o++) accs[o] = 0.f;
#pragma unroll
    for (int k = 0; k < 5; k++)
#pragma unroll
        for (int o = 0; o < 9; o++) accs[o] = fmaf(dot2[k], W2_vvo[k * 9 + o], accs[o]);

    float av0 = 0.f, av1 = 0.f, av2 = 0.f;
#pragma unroll
    for (int k = 0; k < 5; k++) {
        float c = 0.f;
#pragma unroll
        for (int j = 0; j < 5; j++) c = fmaf(s3[j], W2_vsv[k * 5 + j], c);
        float w = W2_vvv[k];
        float cx = (ov[k][1] * v3z - ov[k][2] * v3y) * INV_SQRT2;
        float cy = (ov[k][2] * v3x - ov[k][0] * v3z) * INV_SQRT2;
        float cz = (ov[k][0] * v3y - ov[k][1] * v3x) * INV_SQRT2;
        av0 = fmaf(ov[k][0], c, fmaf(cx, w, av0));
        av1 = fmaf(ov[k][1], c, fmaf(cy, w, av1));
        av2 = fmaf(ov[k][2], c, fmaf(cz, w, av2));
    }
    // ov dead from here

    float p12[20];
#pragma unroll
    for (int i = 0; i < 5; i++)
#pragma unroll
        for (int j = 0; j < 4; j++) p12[i * 4 + j] = s1[i] * s2[j];

    // S = p12 . WS + dot12 * cS   (all pre-scaled by 1/sqrt21)
    float S = dot12 * ws[WS_CS];
#pragma unroll
    for (int ij = 0; ij < 20; ij++) S = fmaf(p12[ij], WSp[ij], S);
    av0 = fmaf(S, v3x, av0);
    av1 = fmaf(S, v3y, av1);
    av2 = fmaf(S, v3z, av2);

    // accs += dot12 * s3 . WV  (45 FMA)
#pragma unroll
    for (int j3 = 0; j3 < 5; j3++) {
        float fv = dot12 * s3[j3];
        const float* w = WV + j3 * 9;
#pragma unroll
        for (int o = 0; o < 9; o++) accs[o] = fmaf(fv, w[o], accs[o]);
    }
    // accs += (p12 x s3) . W12  (100 mul + 900 FMA, the dominant loop)
#pragma unroll
    for (int ij = 0; ij < 20; ij++) {
        float p = p12[ij];
#pragma unroll
        for (int j3 = 0; j3 < 5; j3++) {
            float f = p * s3[j3];
            const float* w = W12 + (ij * 5 + j3) * 9;
#pragma unroll
            for (int o = 0; o < 9; o++) accs[o] = fmaf(f, w[o], accs[o]);
        }
    }

    size_t E3 = (size_t)E * 3;
    size_t b = (size_t)e * 3;
    out[b + 0]          = accs[0] * INV_SQRT105;   // s_rot
    out[b + 1]          = accs[1] * INV_SQRT105;
    out[b + 2]          = accs[2] * INV_SQRT105;
    out[E3 + b + 0]     = accs[3] * INV_SQRT105;   // s_tr
    out[E3 + b + 1]     = accs[4] * INV_SQRT105;
    out[E3 + b + 2]     = accs[5] * INV_SQRT105;
    out[2 * E3 + b + 0] = accs[6] * INV_SQRT105;   // t_rot
    out[2 * E3 + b + 1] = accs[7] * INV_SQRT105;
    out[2 * E3 + b + 2] = accs[8] * INV_SQRT105;
    out[3 * E3 + b + 0] = av0 * INV_SQRT50;        // t_tr
    out[3 * E3 + b + 1] = av1 * INV_SQRT50;
    out[3 * E3 + b + 2] = av2 * INV_SQRT50;
}

extern "C" void kernel_launch(void* const* d_in, const int* in_sizes, int n_in,
                              void* d_out, int out_size, void* d_ws, size_t ws_size,
                              hipStream_t stream) {
    const float* lig    = (const float*)d_in[0];
    const float* rec    = (const float*)d_in[1];
    const float* W1_sso = (const float*)d_in[2];
    const float* W1_svv = (const float*)d_in[3];
    const float* W1_vsv = (const float*)d_in[4];
    const float* W1_vvo = (const float*)d_in[5];
    const float* W1_vvv = (const float*)d_in[6];
    const float* W2_sso = (const float*)d_in[7];
    const float* W2_svv = (const float*)d_in[8];
    const float* W2_vsv = (const float*)d_in[9];
    const float* W2_vvo = (const float*)d_in[10];
    const float* W2_vvv = (const float*)d_in[11];
    float* ws = (float*)d_ws;

    fds_precompose<<<1, 256, 0, stream>>>(W1_sso, W1_vvo, W2_sso, W2_svv, ws);

    int E = in_sizes[0] / 12;  // N*3 / 12 = N/4
    int blocks = (E + 255) / 256;
    fds_kernel<<<blocks, 256, 0, stream>>>(lig, rec, W1_svv, W1_vsv, W1_vvv,
                                           W2_vsv, W2_vvo, W2_vvv, ws,
                                           (float*)d_out, E);
}